// Round 11
// baseline (101.010 us; speedup 1.0000x reference)
//
#include <hip/hip_runtime.h>
#include <hip/hip_bf16.h>
#include <cstddef>

#define NB     2
#define NA     6
#define NWIN   64
#define NTOK   384
#define DIM    128
#define NHEADS 4
#define DHEAD  32

typedef __attribute__((ext_vector_type(8))) short short8;   // 8 bf16 = 4 VGPRs
typedef __attribute__((ext_vector_type(4))) float f32x4;

__device__ __forceinline__ unsigned short f2bf(float f) {
    __hip_bfloat16 h = __float2bfloat16(f);
    return *reinterpret_cast<unsigned short*>(&h);
}
__device__ __forceinline__ float bf2f(unsigned short u) {
    union { unsigned int i; float f; } x; x.i = ((unsigned int)u) << 16; return x.f;
}

// ---------------------------------------------------------------------------
// One-shot weight conversion: fp32 [k][col] -> bf16 transposed [mat][col][k].
// q-matrix (mat 0) pre-scaled by 1/sqrt(32)*head_gate[col>>5].
// ---------------------------------------------------------------------------
__global__ __launch_bounds__(256) void wconv_kernel(
    const float* __restrict__ wq, const float* __restrict__ wk,
    const float* __restrict__ wv, const float* __restrict__ gate,
    unsigned short* __restrict__ wt)
{
    const int e = blockIdx.x * 256 + threadIdx.x;   // 0..49151
    const int mat = e >> 14, i = e & 16383;
    const int kk = i >> 7, c = i & 127;
    const float* src = (mat == 0) ? wq : (mat == 1) ? wk : wv;
    const float s = (mat == 0) ? (0.17677669529663687f * gate[c >> 5]) : 1.0f;
    wt[(mat << 14) + c * DIM + kk] = f2bf(src[i] * s);
}

// ---------------------------------------------------------------------------
// Fused MFMA projection v4 (q+k+v, mode = bid/768): LN(x) @ W + b.
// r9+r10 hybrid: B-frags straight from global wt (96 KB total, L1/L2-hot;
// no LDS W stage, no barrier), with an explicit 2-deep register pipeline
// over col-tiles so loads can't be re-serialized (r9's VGPR=36 failure).
// TB transpose epilogue kept (r10's win over 32x2B scalar stores).
// Only LDS: 19.5 KB TB -> occupancy capped by launch_bounds(256,4) VGPRs.
// mode 0: q -> [b][h][l][t][32] (scale folded); 1: k -> same;
// mode 2: v -> [b][h][l][d][t] (direct ushort4 path)
// ---------------------------------------------------------------------------
__global__ __launch_bounds__(256, 4) void proj_kernel(
    const float* __restrict__ qx, const float* __restrict__ kx,
    const float* __restrict__ vx,
    const float* __restrict__ lnqw, const float* __restrict__ lnqb,
    const float* __restrict__ lnkw, const float* __restrict__ lnkb,
    const float* __restrict__ lnvw, const float* __restrict__ lnvb,
    const float* __restrict__ bq, const float* __restrict__ bk,
    const float* __restrict__ bv, const float* __restrict__ gate,
    const unsigned short* __restrict__ wt,
    unsigned short* __restrict__ qh, unsigned short* __restrict__ kh,
    unsigned short* __restrict__ vh)
{
    __shared__ unsigned short TB[4][16][152];     // 19 KB per-wave transpose

    const int bid  = blockIdx.x;              // 2304 = mode*768 + (b*384+l*6+n)
    const int mode = bid / 768;
    const int rr   = bid - mode * 768;
    const int b = rr / 384, l = (rr / 6) % NWIN, n = rr % 6;

    const float* xin  = (mode == 0) ? qx : (mode == 1) ? kx : vx;
    const float* lw   = (mode == 0) ? lnqw : (mode == 1) ? lnkw : lnvw;
    const float* lb   = (mode == 0) ? lnqb : (mode == 1) ? lnkb : lnvb;
    const float* bias = (mode == 0) ? bq : (mode == 1) ? bk : bv;
    const unsigned short* wtm = wt + (mode << 14);
    unsigned short* outp = (mode == 0) ? qh : (mode == 1) ? kh : vh;

    const int wv_ = threadIdx.x >> 6, lane = threadIdx.x & 63;
    const int g = lane >> 4, qc = lane & 15;
    const int T0 = wv_ * 16;

    // ---- LayerNorm in-register ----
    const float* xp = xin + ((size_t)((b * NA + n) * NWIN + l) * 64 + T0 + qc) * DIM;
    float xv[4][8];
    float s = 0.f, s2 = 0.f;
#pragma unroll
    for (int c = 0; c < 4; ++c) {
        const float4 a0 = *(const float4*)(xp + c * 32 + 8 * g);
        const float4 a1 = *(const float4*)(xp + c * 32 + 8 * g + 4);
        xv[c][0] = a0.x; xv[c][1] = a0.y; xv[c][2] = a0.z; xv[c][3] = a0.w;
        xv[c][4] = a1.x; xv[c][5] = a1.y; xv[c][6] = a1.z; xv[c][7] = a1.w;
#pragma unroll
        for (int u = 0; u < 8; ++u) { s += xv[c][u]; s2 += xv[c][u] * xv[c][u]; }
    }
    s  += __shfl_xor(s, 16);  s  += __shfl_xor(s, 32);
    s2 += __shfl_xor(s2, 16); s2 += __shfl_xor(s2, 32);
    const float mu   = s * (1.0f / 128.0f);
    const float var  = s2 * (1.0f / 128.0f) - mu * mu;
    const float rsig = rsqrtf(var + 1e-5f);

    short8 af[4];
#pragma unroll
    for (int c = 0; c < 4; ++c) {
        const float4 w0 = *(const float4*)(lw + c * 32 + 8 * g);
        const float4 w1 = *(const float4*)(lw + c * 32 + 8 * g + 4);
        const float4 b0 = *(const float4*)(lb + c * 32 + 8 * g);
        const float4 b1 = *(const float4*)(lb + c * 32 + 8 * g + 4);
        af[c][0] = (short)f2bf((xv[c][0] - mu) * rsig * w0.x + b0.x);
        af[c][1] = (short)f2bf((xv[c][1] - mu) * rsig * w0.y + b0.y);
        af[c][2] = (short)f2bf((xv[c][2] - mu) * rsig * w0.z + b0.z);
        af[c][3] = (short)f2bf((xv[c][3] - mu) * rsig * w0.w + b0.w);
        af[c][4] = (short)f2bf((xv[c][4] - mu) * rsig * w1.x + b1.x);
        af[c][5] = (short)f2bf((xv[c][5] - mu) * rsig * w1.y + b1.y);
        af[c][6] = (short)f2bf((xv[c][6] - mu) * rsig * w1.z + b1.z);
        af[c][7] = (short)f2bf((xv[c][7] - mu) * rsig * w1.w + b1.w);
    }

    // ---- 8 col-tiles x 4 k-steps; B-frags from global, 2-deep pipeline ----
    const f32x4 z = {0.f, 0.f, 0.f, 0.f};
    const float gs = 0.17677669529663687f;
    short8 pipe0[4], pipe1[4];
#pragma unroll
    for (int c = 0; c < 4; ++c)
        pipe0[c] = *(const short8*)&wtm[qc * DIM + c * 32 + 8 * g];   // ct=0

#pragma unroll
    for (int ct = 0; ct < 8; ++ct) {
        // prefetch ct+1 into the other pipe (ct compile-time => regs)
        if (ct < 7) {
            const int ncol = (ct + 1) * 16 + qc;
            if (ct & 1) {
#pragma unroll
                for (int c = 0; c < 4; ++c)
                    pipe0[c] = *(const short8*)&wtm[ncol * DIM + c * 32 + 8 * g];
            } else {
#pragma unroll
                for (int c = 0; c < 4; ++c)
                    pipe1[c] = *(const short8*)&wtm[ncol * DIM + c * 32 + 8 * g];
            }
        }
        f32x4 acc = z;
        if (ct & 1) {
#pragma unroll
            for (int c = 0; c < 4; ++c)
                acc = __builtin_amdgcn_mfma_f32_16x16x32_bf16(af[c], pipe1[c], acc, 0, 0, 0);
        } else {
#pragma unroll
            for (int c = 0; c < 4; ++c)
                acc = __builtin_amdgcn_mfma_f32_16x16x32_bf16(af[c], pipe0[c], acc, 0, 0, 0);
        }

        const int col = ct * 16 + qc;
        if (mode == 2) {
            const int head = ct >> 1;
            const int d = (ct & 1) * 16 + qc;
            const float bb = bias[col];
            const size_t hb = (size_t)(b * NHEADS + head) * NWIN + l;
            ushort4 o;
            o.x = f2bf(acc[0] + bb); o.y = f2bf(acc[1] + bb);
            o.z = f2bf(acc[2] + bb); o.w = f2bf(acc[3] + bb);
            *(ushort4*)&outp[(hb * DHEAD + d) * NTOK + n * 64 + T0 + 4 * g] = o;
        } else {
            const float bb = bias[col] * ((mode == 0) ? (gs * gate[ct >> 1]) : 1.0f);
#pragma unroll
            for (int r = 0; r < 4; ++r)
                TB[wv_][4 * g + r][col] = f2bf(acc[r] + bb);
        }
    }

    if (mode != 2) {
        // per-wave transpose readback: lane (g,qc) = (head g, token qc)
        const size_t hbg = (size_t)(b * NHEADS + g) * NWIN + l;
        unsigned short* dst = outp + (hbg * NTOK + n * 64 + T0 + qc) * DHEAD;
#pragma unroll
        for (int j = 0; j < 4; ++j)
            *(short8*)&dst[8 * j] = *(const short8*)&TB[wv_][qc][32 * g + 8 * j];
    }
}

// ---------------------------------------------------------------------------
// MFMA flash attention v3: one block per (b,h,window,q-half), 4 waves x 3
// q-tiles. Grid 1024 (4 blocks/CU). Per kc: K/V frags loaded once, 3
// independent S->exp->pack->write chains then 3 read->PV chains. No barriers.
// ---------------------------------------------------------------------------
__global__ __launch_bounds__(256) void attn_kernel(
    const unsigned short* __restrict__ qh, const unsigned short* __restrict__ kh,
    const unsigned short* __restrict__ vt, unsigned short* __restrict__ aout)
{
    __shared__ unsigned short P[4][3][16][40];   // 15 KB

    const int tid  = threadIdx.x;
    const int w    = tid >> 6;
    const int lane = tid & 63;
    const int g    = lane >> 4;
    const int qc   = lane & 15;

    const int idx = blockIdx.x;                  // b*512 + h*128 + l*2 + half
    const int b = idx >> 9, h = (idx >> 7) & 3, l = (idx >> 1) & 63, half = idx & 1;
    const size_t base = (size_t)((b * NHEADS + h) * NWIN + l) * (NTOK * DHEAD);
    const unsigned short* Qp = qh + base;
    const unsigned short* Kp = kh + base;
    const unsigned short* Vp = vt + base;        // [32][384]

    short8 qf[3];
#pragma unroll
    for (int j = 0; j < 3; ++j)
        qf[j] = *(const short8*)(Qp + (size_t)(((half * 4 + w) * 3 + j) * 16 + qc) * DHEAD + 8 * g);

    f32x4 o0[3], o1[3];
    float psum[3];
    const f32x4 z = {0.f, 0.f, 0.f, 0.f};
#pragma unroll
    for (int j = 0; j < 3; ++j) { o0[j] = z; o1[j] = z; psum[j] = 0.f; }

    for (int kc = 0; kc < 12; ++kc) {
        const int k0 = kc * 32;
        const short8 ka0 = *(const short8*)(Kp + (size_t)(k0 + qc) * DHEAD + 8 * g);
        const short8 ka1 = *(const short8*)(Kp + (size_t)(k0 + 16 + qc) * DHEAD + 8 * g);
        const short8 vb0 = *(const short8*)(Vp + (size_t)qc * NTOK + k0 + 8 * g);
        const short8 vb1 = *(const short8*)(Vp + (size_t)(16 + qc) * NTOK + k0 + 8 * g);

#pragma unroll
        for (int j = 0; j < 3; ++j) {
            f32x4 s0 = __builtin_amdgcn_mfma_f32_16x16x32_bf16(ka0, qf[j], z, 0, 0, 0);
            f32x4 s1 = __builtin_amdgcn_mfma_f32_16x16x32_bf16(ka1, qf[j], z, 0, 0, 0);
            const float e0 = __expf(s0[0]), e1 = __expf(s0[1]), e2 = __expf(s0[2]), e3 = __expf(s0[3]);
            const float e4 = __expf(s1[0]), e5 = __expf(s1[1]), e6 = __expf(s1[2]), e7 = __expf(s1[3]);
            psum[j] += ((e0 + e1) + (e2 + e3)) + ((e4 + e5) + (e6 + e7));
            ushort4 pw0, pw1;
            pw0.x = f2bf(e0); pw0.y = f2bf(e1); pw0.z = f2bf(e2); pw0.w = f2bf(e3);
            pw1.x = f2bf(e4); pw1.y = f2bf(e5); pw1.z = f2bf(e6); pw1.w = f2bf(e7);
            *(ushort4*)&P[w][j][qc][4 * g]      = pw0;
            *(ushort4*)&P[w][j][qc][16 + 4 * g] = pw1;
        }
#pragma unroll
        for (int j = 0; j < 3; ++j) {
            const short8 pa = *(const short8*)&P[w][j][qc][8 * g];
            o0[j] = __builtin_amdgcn_mfma_f32_16x16x32_bf16(pa, vb0, o0[j], 0, 0, 0);
            o1[j] = __builtin_amdgcn_mfma_f32_16x16x32_bf16(pa, vb1, o1[j], 0, 0, 0);
        }
    }

#pragma unroll
    for (int j = 0; j < 3; ++j) {
        float ps = psum[j];
        ps += __shfl_xor(ps, 16);
        ps += __shfl_xor(ps, 32);
        const float inv = 1.0f / ps;
        const int q0 = ((half * 4 + w) * 3 + j) * 16;
        const size_t ob = ((size_t)(b * NWIN + l) * NTOK + q0) * (NHEADS * DHEAD) + h * DHEAD + qc;
#pragma unroll
        for (int r = 0; r < 4; ++r) {
            const float iv = __shfl(inv, 4 * g + r);
            aout[ob + (size_t)(4 * g + r) * (NHEADS * DHEAD)]      = f2bf(o0[j][r] * iv);
            aout[ob + (size_t)(4 * g + r) * (NHEADS * DHEAD) + 16] = f2bf(o1[j][r] * iv);
        }
    }
}

// ---------------------------------------------------------------------------
// Output projection: mean over n commutes with (@ wp + bp). One block per
// (b, window, col-half) -> 256 blocks. a is bf16.
// ---------------------------------------------------------------------------
__global__ __launch_bounds__(256) void outproj_kernel(
    const unsigned short* __restrict__ a, const float* __restrict__ wp,
    const float* __restrict__ bp, const float* __restrict__ skip,
    float* __restrict__ outp)
{
    __shared__ float at[DIM * 68];       // abar transposed [dim][w], 34 KB
    __shared__ float wl[DIM * 64];       // [k][64 cols] 32 KB

    const int tid = threadIdx.x;
    const int bid = blockIdx.x;
    const int b = bid >> 7, l = (bid >> 1) & 63, cg = bid & 1;
    const int c0 = cg * 64;

#pragma unroll
    for (int rep = 0; rep < 8; ++rep) {
        const int idx = rep * 256 + tid;
        const int row = idx >> 4, cc4 = idx & 15;
        *(float4*)&wl[row * 64 + cc4 * 4] = *(const float4*)&wp[row * 128 + c0 + cc4 * 4];
    }

    const size_t abase = (size_t)(b * NWIN + l) * NTOK * DIM;
#pragma unroll
    for (int r = 0; r < 32; ++r) {
        const int f = tid + 256 * r;     // f = w*128 + d
        const int w_ = f >> 7, d = f & 127;
        float s = 0.f;
#pragma unroll
        for (int n = 0; n < NA; ++n)
            s += bf2f(a[abase + (size_t)(n * 64 + w_) * DIM + d]);
        at[d * 68 + w_] = s * (1.0f / 6.0f);
    }
    __syncthreads();

    const int cx = tid & 15, ty = tid >> 4;   // 4 cols x 4 tokens per thread
    float acc[4][4];
#pragma unroll
    for (int i = 0; i < 4; ++i)
#pragma unroll
        for (int j = 0; j < 4; ++j) acc[i][j] = 0.f;

#pragma unroll 4
    for (int i = 0; i < DIM; ++i) {
        const float4 wa = *(const float4*)&wl[i * 64 + 4 * cx];
        const float4 aa = *(const float4*)&at[i * 68 + 4 * ty];
        acc[0][0] += aa.x * wa.x; acc[0][1] += aa.x * wa.y; acc[0][2] += aa.x * wa.z; acc[0][3] += aa.x * wa.w;
        acc[1][0] += aa.y * wa.x; acc[1][1] += aa.y * wa.y; acc[1][2] += aa.y * wa.z; acc[1][3] += aa.y * wa.w;
        acc[2][0] += aa.z * wa.x; acc[2][1] += aa.z * wa.y; acc[2][2] += aa.z * wa.z; acc[2][3] += aa.z * wa.w;
        acc[3][0] += aa.w * wa.x; acc[3][1] += aa.w * wa.y; acc[3][2] += aa.w * wa.z; acc[3][3] += aa.w * wa.w;
    }

    const float4 bb = *(const float4*)&bp[c0 + 4 * cx];
#pragma unroll
    for (int u = 0; u < 4; ++u) {
        const int w_ = 4 * ty + u;
        const size_t oidx = ((size_t)(b * NWIN + l) * 64 + w_) * DIM + c0 + 4 * cx;
        const float4 sk = *(const float4*)&skip[oidx];
        float4 o;
        o.x = acc[u][0] + bb.x + sk.x;
        o.y = acc[u][1] + bb.y + sk.y;
        o.z = acc[u][2] + bb.z + sk.z;
        o.w = acc[u][3] + bb.w + sk.w;
        *(float4*)&outp[oidx] = o;
    }
}

extern "C" void kernel_launch(void* const* d_in, const int* in_sizes, int n_in,
                              void* d_out, int out_size, void* d_ws, size_t ws_size,
                              hipStream_t stream) {
    const float* q      = (const float*)d_in[0];
    const float* k      = (const float*)d_in[1];
    const float* v      = (const float*)d_in[2];
    const float* skip   = (const float*)d_in[3];
    const float* gate   = (const float*)d_in[4];
    const float* ln_q_w = (const float*)d_in[5];
    const float* ln_q_b = (const float*)d_in[6];
    const float* ln_k_w = (const float*)d_in[7];
    const float* ln_k_b = (const float*)d_in[8];
    const float* ln_v_w = (const float*)d_in[9];
    const float* ln_v_b = (const float*)d_in[10];
    const float* wq     = (const float*)d_in[11];
    const float* bq     = (const float*)d_in[12];
    const float* wk     = (const float*)d_in[13];
    const float* bk     = (const float*)d_in[14];
    const float* wv     = (const float*)d_in[15];
    const float* bv     = (const float*)d_in[16];
    const float* wp     = (const float*)d_in[17];
    const float* bp     = (const float*)d_in[18];
    float* outp = (float*)d_out;

    const size_t per = (size_t)NB * NHEADS * NWIN * NTOK * DHEAD;  // 6,291,456
    unsigned short* qh = (unsigned short*)d_ws;
    unsigned short* kh = qh + per;
    unsigned short* vh = kh + per;
    unsigned short* wt = vh + per;                 // 3*16384 bf16
    unsigned short* a  = wt + 3 * 16384;           // [b][l][t][128] bf16

    wconv_kernel<<<192, 256, 0, stream>>>(wq, wk, wv, gate, wt);
    proj_kernel<<<3 * NB * NWIN * NA, 256, 0, stream>>>(
        q, k, v, ln_q_w, ln_q_b, ln_k_w, ln_k_b, ln_v_w, ln_v_b,
        bq, bk, bv, gate, wt, qh, kh, vh);
    attn_kernel<<<NB * NHEADS * NWIN * 2, 256, 0, stream>>>(qh, kh, vh, a);
    outproj_kernel<<<NB * NWIN * 2, 256, 0, stream>>>(a, wp, bp, skip, outp);
}

// Round 12
// 80.611 us; speedup vs baseline: 1.2530x; 1.2530x over previous
//
#include <hip/hip_runtime.h>
#include <hip/hip_bf16.h>
#include <cstddef>

#define NB     2
#define NA     6
#define NWIN   64
#define NTOK   384
#define DIM    128
#define NHEADS 4
#define DHEAD  32

typedef __attribute__((ext_vector_type(8))) short short8;   // 8 bf16 = 4 VGPRs
typedef __attribute__((ext_vector_type(4))) float f32x4;

__device__ __forceinline__ unsigned short f2bf(float f) {
    __hip_bfloat16 h = __float2bfloat16(f);
    return *reinterpret_cast<unsigned short*>(&h);
}
__device__ __forceinline__ float bf2f(unsigned short u) {
    union { unsigned int i; float f; } x; x.i = ((unsigned int)u) << 16; return x.f;
}

// ---------------------------------------------------------------------------
// One-shot weight conversion: fp32 [k][col] -> bf16 transposed [mat][col][k].
// q-matrix (mat 0) pre-scaled by 1/sqrt(32)*head_gate[col>>5].
// ---------------------------------------------------------------------------
__global__ __launch_bounds__(256) void wconv_kernel(
    const float* __restrict__ wq, const float* __restrict__ wk,
    const float* __restrict__ wv, const float* __restrict__ gate,
    unsigned short* __restrict__ wt)
{
    const int e = blockIdx.x * 256 + threadIdx.x;   // 0..49151
    const int mat = e >> 14, i = e & 16383;
    const int kk = i >> 7, c = i & 127;
    const float* src = (mat == 0) ? wq : (mat == 1) ? wk : wv;
    const float s = (mat == 0) ? (0.17677669529663687f * gate[c >> 5]) : 1.0f;
    wt[(mat << 14) + c * DIM + kk] = f2bf(src[i] * s);
}

// ---------------------------------------------------------------------------
// Fused MFMA projection v5 (q+k+v, mode = bid/768): LN(x) @ W + b.
// Lessons r9-r11: B-frags from global never pipeline (compiler sinks loads,
// VGPR=36) -> W must be LDS-fed (r10, proven). r10's cost was 52 KB LDS
// (3 blocks/CU). Fix: delete the TB transpose buffer by SWAPPING the mfma
// operands for q/k — mfma(W, x) = D^T, so lane (g,qc) holds token qc x
// 4 CONSECUTIVE cols (ct*16+4g..+3) -> one ushort4 contiguous store per ct.
// A/B frag lane layouts are symmetric, so both paths read the same swizzled
// Wl words; only operand order differs. LDS 32 KB -> 5 blocks/CU.
// mode 0: q -> [b][h][l][t][32] (scale folded); 1: k -> same;
// mode 2: v -> [b][h][l][d][t] (unswapped: D rows = tokens -> ushort4)
// ---------------------------------------------------------------------------
__global__ __launch_bounds__(256, 4) void proj_kernel(
    const float* __restrict__ qx, const float* __restrict__ kx,
    const float* __restrict__ vx,
    const float* __restrict__ lnqw, const float* __restrict__ lnqb,
    const float* __restrict__ lnkw, const float* __restrict__ lnkb,
    const float* __restrict__ lnvw, const float* __restrict__ lnvb,
    const float* __restrict__ bq, const float* __restrict__ bk,
    const float* __restrict__ bv, const float* __restrict__ gate,
    const unsigned short* __restrict__ wt,
    unsigned short* __restrict__ qh, unsigned short* __restrict__ kh,
    unsigned short* __restrict__ vh)
{
    __shared__ unsigned short Wl[DIM * DIM];      // 32 KB swizzled [col][k]

    const int bid  = blockIdx.x;              // 2304 = mode*768 + (b*384+l*6+n)
    const int mode = bid / 768;
    const int rr   = bid - mode * 768;
    const int b = rr / 384, l = (rr / 6) % NWIN, n = rr % 6;

    const float* xin  = (mode == 0) ? qx : (mode == 1) ? kx : vx;
    const float* lw   = (mode == 0) ? lnqw : (mode == 1) ? lnkw : lnvw;
    const float* lb   = (mode == 0) ? lnqb : (mode == 1) ? lnkb : lnvb;
    const float* bias = (mode == 0) ? bq : (mode == 1) ? bk : bv;
    const unsigned short* wtm = wt + (mode << 14);
    unsigned short* outp = (mode == 0) ? qh : (mode == 1) ? kh : vh;

    // stage W: 32 KB, 16B/thread/iter, XOR-swizzled (G4)
#pragma unroll
    for (int it = 0; it < 8; ++it) {
        const int e = it * 256 + threadIdx.x;     // 16B chunk id
        const int col = e >> 4, k8 = (e & 15) * 8;
        *(short8*)&Wl[col * DIM + (k8 ^ ((col & 7) << 3))] =
            *(const short8*)&wtm[col * DIM + k8];
    }

    const int wv_ = threadIdx.x >> 6, lane = threadIdx.x & 63;
    const int g = lane >> 4, qc = lane & 15;
    const int T0 = wv_ * 16;

    // ---- LayerNorm in-register (overlaps W staging; barrier after) ----
    const float* xp = xin + ((size_t)((b * NA + n) * NWIN + l) * 64 + T0 + qc) * DIM;
    float xv[4][8];
    float s = 0.f, s2 = 0.f;
#pragma unroll
    for (int c = 0; c < 4; ++c) {
        const float4 a0 = *(const float4*)(xp + c * 32 + 8 * g);
        const float4 a1 = *(const float4*)(xp + c * 32 + 8 * g + 4);
        xv[c][0] = a0.x; xv[c][1] = a0.y; xv[c][2] = a0.z; xv[c][3] = a0.w;
        xv[c][4] = a1.x; xv[c][5] = a1.y; xv[c][6] = a1.z; xv[c][7] = a1.w;
#pragma unroll
        for (int u = 0; u < 8; ++u) { s += xv[c][u]; s2 += xv[c][u] * xv[c][u]; }
    }
    s  += __shfl_xor(s, 16);  s  += __shfl_xor(s, 32);
    s2 += __shfl_xor(s2, 16); s2 += __shfl_xor(s2, 32);
    const float mu   = s * (1.0f / 128.0f);
    const float var  = s2 * (1.0f / 128.0f) - mu * mu;
    const float rsig = rsqrtf(var + 1e-5f);

    short8 af[4];
#pragma unroll
    for (int c = 0; c < 4; ++c) {
        const float4 w0 = *(const float4*)(lw + c * 32 + 8 * g);
        const float4 w1 = *(const float4*)(lw + c * 32 + 8 * g + 4);
        const float4 b0 = *(const float4*)(lb + c * 32 + 8 * g);
        const float4 b1 = *(const float4*)(lb + c * 32 + 8 * g + 4);
        af[c][0] = (short)f2bf((xv[c][0] - mu) * rsig * w0.x + b0.x);
        af[c][1] = (short)f2bf((xv[c][1] - mu) * rsig * w0.y + b0.y);
        af[c][2] = (short)f2bf((xv[c][2] - mu) * rsig * w0.z + b0.z);
        af[c][3] = (short)f2bf((xv[c][3] - mu) * rsig * w0.w + b0.w);
        af[c][4] = (short)f2bf((xv[c][4] - mu) * rsig * w1.x + b1.x);
        af[c][5] = (short)f2bf((xv[c][5] - mu) * rsig * w1.y + b1.y);
        af[c][6] = (short)f2bf((xv[c][6] - mu) * rsig * w1.z + b1.z);
        af[c][7] = (short)f2bf((xv[c][7] - mu) * rsig * w1.w + b1.w);
    }
    __syncthreads();    // W staged

    const f32x4 z = {0.f, 0.f, 0.f, 0.f};
    const float gs = 0.17677669529663687f;
    const int swz = (qc & 7) << 3;            // col&7 == qc&7 (ct*16 ≡ 0 mod 8)

#pragma unroll
    for (int ct = 0; ct < 8; ++ct) {
        const int col = ct * 16 + qc;
        short8 wf[4];
#pragma unroll
        for (int c = 0; c < 4; ++c)
            wf[c] = *(const short8*)&Wl[col * DIM + ((c * 32 + 8 * g) ^ swz)];

        f32x4 acc = z;
        if (mode == 2) {
            // unswapped: D rows = tokens (4g+r), col = W-col qc -> [d][t] store
#pragma unroll
            for (int c = 0; c < 4; ++c)
                acc = __builtin_amdgcn_mfma_f32_16x16x32_bf16(af[c], wf[c], acc, 0, 0, 0);
            const int head = ct >> 1;
            const int d = (ct & 1) * 16 + qc;
            const float bb = bias[col];
            const size_t hb = (size_t)(b * NHEADS + head) * NWIN + l;
            ushort4 o;
            o.x = f2bf(acc[0] + bb); o.y = f2bf(acc[1] + bb);
            o.z = f2bf(acc[2] + bb); o.w = f2bf(acc[3] + bb);
            *(ushort4*)&outp[(hb * DHEAD + d) * NTOK + n * 64 + T0 + 4 * g] = o;
        } else {
            // swapped: D^T -> lane holds token qc, cols ct*16+4g..+3 (contig)
#pragma unroll
            for (int c = 0; c < 4; ++c)
                acc = __builtin_amdgcn_mfma_f32_16x16x32_bf16(wf[c], af[c], acc, 0, 0, 0);
            const int head = ct >> 1;                 // 4g+3 < 16: no head cross
            const int d0 = (ct & 1) * 16 + 4 * g;
            const float hs = (mode == 0) ? (gs * gate[head]) : 1.0f;
            const float4 b4 = *(const float4*)&bias[ct * 16 + 4 * g];
            const size_t hb = (size_t)(b * NHEADS + head) * NWIN + l;
            const int t = n * 64 + T0 + qc;
            ushort4 o;
            o.x = f2bf(acc[0] + b4.x * hs); o.y = f2bf(acc[1] + b4.y * hs);
            o.z = f2bf(acc[2] + b4.z * hs); o.w = f2bf(acc[3] + b4.w * hs);
            *(ushort4*)&outp[(hb * NTOK + t) * DHEAD + d0] = o;
        }
    }
}

// ---------------------------------------------------------------------------
// MFMA flash attention v3: one block per (b,h,window,q-half), 4 waves x 3
// q-tiles. Grid 1024 (4 blocks/CU). Per kc: K/V frags loaded once, 3
// independent S->exp->pack->write chains then 3 read->PV chains. No barriers.
// ---------------------------------------------------------------------------
__global__ __launch_bounds__(256) void attn_kernel(
    const unsigned short* __restrict__ qh, const unsigned short* __restrict__ kh,
    const unsigned short* __restrict__ vt, unsigned short* __restrict__ aout)
{
    __shared__ unsigned short P[4][3][16][40];   // 15 KB

    const int tid  = threadIdx.x;
    const int w    = tid >> 6;
    const int lane = tid & 63;
    const int g    = lane >> 4;
    const int qc   = lane & 15;

    const int idx = blockIdx.x;                  // b*512 + h*128 + l*2 + half
    const int b = idx >> 9, h = (idx >> 7) & 3, l = (idx >> 1) & 63, half = idx & 1;
    const size_t base = (size_t)((b * NHEADS + h) * NWIN + l) * (NTOK * DHEAD);
    const unsigned short* Qp = qh + base;
    const unsigned short* Kp = kh + base;
    const unsigned short* Vp = vt + base;        // [32][384]

    short8 qf[3];
#pragma unroll
    for (int j = 0; j < 3; ++j)
        qf[j] = *(const short8*)(Qp + (size_t)(((half * 4 + w) * 3 + j) * 16 + qc) * DHEAD + 8 * g);

    f32x4 o0[3], o1[3];
    float psum[3];
    const f32x4 z = {0.f, 0.f, 0.f, 0.f};
#pragma unroll
    for (int j = 0; j < 3; ++j) { o0[j] = z; o1[j] = z; psum[j] = 0.f; }

    for (int kc = 0; kc < 12; ++kc) {
        const int k0 = kc * 32;
        const short8 ka0 = *(const short8*)(Kp + (size_t)(k0 + qc) * DHEAD + 8 * g);
        const short8 ka1 = *(const short8*)(Kp + (size_t)(k0 + 16 + qc) * DHEAD + 8 * g);
        const short8 vb0 = *(const short8*)(Vp + (size_t)qc * NTOK + k0 + 8 * g);
        const short8 vb1 = *(const short8*)(Vp + (size_t)(16 + qc) * NTOK + k0 + 8 * g);

#pragma unroll
        for (int j = 0; j < 3; ++j) {
            f32x4 s0 = __builtin_amdgcn_mfma_f32_16x16x32_bf16(ka0, qf[j], z, 0, 0, 0);
            f32x4 s1 = __builtin_amdgcn_mfma_f32_16x16x32_bf16(ka1, qf[j], z, 0, 0, 0);
            const float e0 = __expf(s0[0]), e1 = __expf(s0[1]), e2 = __expf(s0[2]), e3 = __expf(s0[3]);
            const float e4 = __expf(s1[0]), e5 = __expf(s1[1]), e6 = __expf(s1[2]), e7 = __expf(s1[3]);
            psum[j] += ((e0 + e1) + (e2 + e3)) + ((e4 + e5) + (e6 + e7));
            ushort4 pw0, pw1;
            pw0.x = f2bf(e0); pw0.y = f2bf(e1); pw0.z = f2bf(e2); pw0.w = f2bf(e3);
            pw1.x = f2bf(e4); pw1.y = f2bf(e5); pw1.z = f2bf(e6); pw1.w = f2bf(e7);
            *(ushort4*)&P[w][j][qc][4 * g]      = pw0;
            *(ushort4*)&P[w][j][qc][16 + 4 * g] = pw1;
        }
#pragma unroll
        for (int j = 0; j < 3; ++j) {
            const short8 pa = *(const short8*)&P[w][j][qc][8 * g];
            o0[j] = __builtin_amdgcn_mfma_f32_16x16x32_bf16(pa, vb0, o0[j], 0, 0, 0);
            o1[j] = __builtin_amdgcn_mfma_f32_16x16x32_bf16(pa, vb1, o1[j], 0, 0, 0);
        }
    }

#pragma unroll
    for (int j = 0; j < 3; ++j) {
        float ps = psum[j];
        ps += __shfl_xor(ps, 16);
        ps += __shfl_xor(ps, 32);
        const float inv = 1.0f / ps;
        const int q0 = ((half * 4 + w) * 3 + j) * 16;
        const size_t ob = ((size_t)(b * NWIN + l) * NTOK + q0) * (NHEADS * DHEAD) + h * DHEAD + qc;
#pragma unroll
        for (int r = 0; r < 4; ++r) {
            const float iv = __shfl(inv, 4 * g + r);
            aout[ob + (size_t)(4 * g + r) * (NHEADS * DHEAD)]      = f2bf(o0[j][r] * iv);
            aout[ob + (size_t)(4 * g + r) * (NHEADS * DHEAD) + 16] = f2bf(o1[j][r] * iv);
        }
    }
}

// ---------------------------------------------------------------------------
// Output projection: mean over n commutes with (@ wp + bp). One block per
// (b, window, col-half) -> 256 blocks. a is bf16.
// ---------------------------------------------------------------------------
__global__ __launch_bounds__(256) void outproj_kernel(
    const unsigned short* __restrict__ a, const float* __restrict__ wp,
    const float* __restrict__ bp, const float* __restrict__ skip,
    float* __restrict__ outp)
{
    __shared__ float at[DIM * 68];       // abar transposed [dim][w], 34 KB
    __shared__ float wl[DIM * 64];       // [k][64 cols] 32 KB

    const int tid = threadIdx.x;
    const int bid = blockIdx.x;
    const int b = bid >> 7, l = (bid >> 1) & 63, cg = bid & 1;
    const int c0 = cg * 64;

#pragma unroll
    for (int rep = 0; rep < 8; ++rep) {
        const int idx = rep * 256 + tid;
        const int row = idx >> 4, cc4 = idx & 15;
        *(float4*)&wl[row * 64 + cc4 * 4] = *(const float4*)&wp[row * 128 + c0 + cc4 * 4];
    }

    const size_t abase = (size_t)(b * NWIN + l) * NTOK * DIM;
#pragma unroll
    for (int r = 0; r < 32; ++r) {
        const int f = tid + 256 * r;     // f = w*128 + d
        const int w_ = f >> 7, d = f & 127;
        float s = 0.f;
#pragma unroll
        for (int n = 0; n < NA; ++n)
            s += bf2f(a[abase + (size_t)(n * 64 + w_) * DIM + d]);
        at[d * 68 + w_] = s * (1.0f / 6.0f);
    }
    __syncthreads();

    const int cx = tid & 15, ty = tid >> 4;   // 4 cols x 4 tokens per thread
    float acc[4][4];
#pragma unroll
    for (int i = 0; i < 4; ++i)
#pragma unroll
        for (int j = 0; j < 4; ++j) acc[i][j] = 0.f;

#pragma unroll 4
    for (int i = 0; i < DIM; ++i) {
        const float4 wa = *(const float4*)&wl[i * 64 + 4 * cx];
        const float4 aa = *(const float4*)&at[i * 68 + 4 * ty];
        acc[0][0] += aa.x * wa.x; acc[0][1] += aa.x * wa.y; acc[0][2] += aa.x * wa.z; acc[0][3] += aa.x * wa.w;
        acc[1][0] += aa.y * wa.x; acc[1][1] += aa.y * wa.y; acc[1][2] += aa.y * wa.z; acc[1][3] += aa.y * wa.w;
        acc[2][0] += aa.z * wa.x; acc[2][1] += aa.z * wa.y; acc[2][2] += aa.z * wa.z; acc[2][3] += aa.z * wa.w;
        acc[3][0] += aa.w * wa.x; acc[3][1] += aa.w * wa.y; acc[3][2] += aa.w * wa.z; acc[3][3] += aa.w * wa.w;
    }

    const float4 bb = *(const float4*)&bp[c0 + 4 * cx];
#pragma unroll
    for (int u = 0; u < 4; ++u) {
        const int w_ = 4 * ty + u;
        const size_t oidx = ((size_t)(b * NWIN + l) * 64 + w_) * DIM + c0 + 4 * cx;
        const float4 sk = *(const float4*)&skip[oidx];
        float4 o;
        o.x = acc[u][0] + bb.x + sk.x;
        o.y = acc[u][1] + bb.y + sk.y;
        o.z = acc[u][2] + bb.z + sk.z;
        o.w = acc[u][3] + bb.w + sk.w;
        *(float4*)&outp[oidx] = o;
    }
}

extern "C" void kernel_launch(void* const* d_in, const int* in_sizes, int n_in,
                              void* d_out, int out_size, void* d_ws, size_t ws_size,
                              hipStream_t stream) {
    const float* q      = (const float*)d_in[0];
    const float* k      = (const float*)d_in[1];
    const float* v      = (const float*)d_in[2];
    const float* skip   = (const float*)d_in[3];
    const float* gate   = (const float*)d_in[4];
    const float* ln_q_w = (const float*)d_in[5];
    const float* ln_q_b = (const float*)d_in[6];
    const float* ln_k_w = (const float*)d_in[7];
    const float* ln_k_b = (const float*)d_in[8];
    const float* ln_v_w = (const float*)d_in[9];
    const float* ln_v_b = (const float*)d_in[10];
    const float* wq     = (const float*)d_in[11];
    const float* bq     = (const float*)d_in[12];
    const float* wk     = (const float*)d_in[13];
    const float* bk     = (const float*)d_in[14];
    const float* wv     = (const float*)d_in[15];
    const float* bv     = (const float*)d_in[16];
    const float* wp     = (const float*)d_in[17];
    const float* bp     = (const float*)d_in[18];
    float* outp = (float*)d_out;

    const size_t per = (size_t)NB * NHEADS * NWIN * NTOK * DHEAD;  // 6,291,456
    unsigned short* qh = (unsigned short*)d_ws;
    unsigned short* kh = qh + per;
    unsigned short* vh = kh + per;
    unsigned short* wt = vh + per;                 // 3*16384 bf16
    unsigned short* a  = wt + 3 * 16384;           // [b][l][t][128] bf16

    wconv_kernel<<<192, 256, 0, stream>>>(wq, wk, wv, gate, wt);
    proj_kernel<<<3 * NB * NWIN * NA, 256, 0, stream>>>(
        q, k, v, ln_q_w, ln_q_b, ln_k_w, ln_k_b, ln_v_w, ln_v_b,
        bq, bk, bv, gate, wt, qh, kh, vh);
    attn_kernel<<<NB * NHEADS * NWIN * 2, 256, 0, stream>>>(qh, kh, vh, a);
    outproj_kernel<<<NB * NWIN * 2, 256, 0, stream>>>(a, wp, bp, skip, outp);
}

// Round 14
// 75.094 us; speedup vs baseline: 1.3451x; 1.0735x over previous
//
#include <hip/hip_runtime.h>
#include <hip/hip_bf16.h>
#include <cstddef>

#define NB     2
#define NA     6
#define NWIN   64
#define NTOK   384
#define DIM    128
#define NHEADS 4
#define DHEAD  32

typedef __attribute__((ext_vector_type(8))) short short8;   // 8 bf16 = 4 VGPRs
typedef __attribute__((ext_vector_type(4))) float f32x4;

__device__ __forceinline__ unsigned short f2bf(float f) {
    __hip_bfloat16 h = __float2bfloat16(f);
    return *reinterpret_cast<unsigned short*>(&h);
}
__device__ __forceinline__ float bf2f(unsigned short u) {
    union { unsigned int i; float f; } x; x.i = ((unsigned int)u) << 16; return x.f;
}

// ---------------------------------------------------------------------------
// One-shot weight conversion: fp32 [k][col] -> bf16 transposed [mat][col][k].
// q-matrix (mat 0) pre-scaled by 1/sqrt(32)*head_gate[col>>5].
// ---------------------------------------------------------------------------
__global__ __launch_bounds__(256) void wconv_kernel(
    const float* __restrict__ wq, const float* __restrict__ wk,
    const float* __restrict__ wv, const float* __restrict__ gate,
    unsigned short* __restrict__ wt)
{
    const int e = blockIdx.x * 256 + threadIdx.x;   // 0..49151
    const int mat = e >> 14, i = e & 16383;
    const int kk = i >> 7, c = i & 127;
    const float* src = (mat == 0) ? wq : (mat == 1) ? wk : wv;
    const float s = (mat == 0) ? (0.17677669529663687f * gate[c >> 5]) : 1.0f;
    wt[(mat << 14) + c * DIM + kk] = f2bf(src[i] * s);
}

// LN one 16-token tile into bf16 A-frags (lane owns token qc, dims via g)
__device__ __forceinline__ void ln_tile(
    const float* __restrict__ xp, const float* __restrict__ lw,
    const float* __restrict__ lb, int g, short8* __restrict__ af)
{
    float xv[4][8];
    float s = 0.f, s2 = 0.f;
#pragma unroll
    for (int c = 0; c < 4; ++c) {
        const float4 a0 = *(const float4*)(xp + c * 32 + 8 * g);
        const float4 a1 = *(const float4*)(xp + c * 32 + 8 * g + 4);
        xv[c][0] = a0.x; xv[c][1] = a0.y; xv[c][2] = a0.z; xv[c][3] = a0.w;
        xv[c][4] = a1.x; xv[c][5] = a1.y; xv[c][6] = a1.z; xv[c][7] = a1.w;
#pragma unroll
        for (int u = 0; u < 8; ++u) { s += xv[c][u]; s2 += xv[c][u] * xv[c][u]; }
    }
    s  += __shfl_xor(s, 16);  s  += __shfl_xor(s, 32);
    s2 += __shfl_xor(s2, 16); s2 += __shfl_xor(s2, 32);
    const float mu   = s * (1.0f / 128.0f);
    const float var  = s2 * (1.0f / 128.0f) - mu * mu;
    const float rsig = rsqrtf(var + 1e-5f);
#pragma unroll
    for (int c = 0; c < 4; ++c) {
        const float4 w0 = *(const float4*)(lw + c * 32 + 8 * g);
        const float4 w1 = *(const float4*)(lw + c * 32 + 8 * g + 4);
        const float4 b0 = *(const float4*)(lb + c * 32 + 8 * g);
        const float4 b1 = *(const float4*)(lb + c * 32 + 8 * g + 4);
        short8 o;
        o[0] = (short)f2bf((xv[c][0] - mu) * rsig * w0.x + b0.x);
        o[1] = (short)f2bf((xv[c][1] - mu) * rsig * w0.y + b0.y);
        o[2] = (short)f2bf((xv[c][2] - mu) * rsig * w0.z + b0.z);
        o[3] = (short)f2bf((xv[c][3] - mu) * rsig * w0.w + b0.w);
        o[4] = (short)f2bf((xv[c][4] - mu) * rsig * w1.x + b1.x);
        o[5] = (short)f2bf((xv[c][5] - mu) * rsig * w1.y + b1.y);
        o[6] = (short)f2bf((xv[c][6] - mu) * rsig * w1.z + b1.z);
        o[7] = (short)f2bf((xv[c][7] - mu) * rsig * w1.w + b1.w);
        af[c] = o;
    }
}

// ---------------------------------------------------------------------------
// Fused MFMA projection v6 (q+k+v): LN(x) @ W + b, W amortized over 3 units.
// r12 post-mortem: 2304 tiny blocks each paid {W-stage + barrier + LN-latency}
// for 32 MFMAs -> latency-bound at 45us across 3 structural variants.
// v6: grid 768 (3 blocks/CU, all resident). Each block stages W ONCE, then
// processes 3 x 16-token units per wave. Loop inverted: per ct-tile the
// 4 ds_read_b128 feed 12 MFMAs (3 independent 4-deep acc chains = 3-way ILP).
// q/k use swapped-operand mfma (D^T -> contiguous ushort4 stores, r12-proven).
// mode 0: q (scale folded into wt); 1: k; 2: v -> [b][h][l][d][t]
// ---------------------------------------------------------------------------
__global__ __launch_bounds__(256) void proj_kernel(
    const float* __restrict__ qx, const float* __restrict__ kx,
    const float* __restrict__ vx,
    const float* __restrict__ lnqw, const float* __restrict__ lnqb,
    const float* __restrict__ lnkw, const float* __restrict__ lnkb,
    const float* __restrict__ lnvw, const float* __restrict__ lnvb,
    const float* __restrict__ bq, const float* __restrict__ bk,
    const float* __restrict__ bv, const float* __restrict__ gate,
    const unsigned short* __restrict__ wt,
    unsigned short* __restrict__ qh, unsigned short* __restrict__ kh,
    unsigned short* __restrict__ vh)
{
    __shared__ unsigned short Wl[DIM * DIM];      // 32 KB swizzled [col][k]

    const int bid  = blockIdx.x;              // 768 = mode*256 + rr
    const int mode = bid >> 8;
    const int rr   = bid & 255;               // b*128 + l*2 + ng
    const int b = rr >> 7, l = (rr >> 1) & 63, ng = rr & 1;

    const float* xin  = (mode == 0) ? qx : (mode == 1) ? kx : vx;
    const float* lw   = (mode == 0) ? lnqw : (mode == 1) ? lnkw : lnvw;
    const float* lb   = (mode == 0) ? lnqb : (mode == 1) ? lnkb : lnvb;
    const float* bias = (mode == 0) ? bq : (mode == 1) ? bk : bv;
    const unsigned short* wtm = wt + (mode << 14);
    unsigned short* outp = (mode == 0) ? qh : (mode == 1) ? kh : vh;

    // stage W: 32 KB, 16B/thread/iter, XOR-swizzled (G4)
#pragma unroll
    for (int it = 0; it < 8; ++it) {
        const int e = it * 256 + threadIdx.x;     // 16B chunk id
        const int col = e >> 4, k8 = (e & 15) * 8;
        *(short8*)&Wl[col * DIM + (k8 ^ ((col & 7) << 3))] =
            *(const short8*)&wtm[col * DIM + k8];
    }

    const int wv_ = threadIdx.x >> 6, lane = threadIdx.x & 63;
    const int g = lane >> 4, qc = lane & 15;
    const int T0 = wv_ * 16;

    // ---- LN for the 3 agent-units (named frag sets; overlaps W staging) ----
    const size_t xbase = (size_t)(b * NA) * (NWIN * 64) + (size_t)l * 64 + T0 + qc;
    const int n0 = ng * 3;
    short8 af0[4], af1[4], af2[4];
    ln_tile(xin + (xbase + (size_t)(n0 + 0) * (NWIN * 64)) * DIM, lw, lb, g, af0);
    ln_tile(xin + (xbase + (size_t)(n0 + 1) * (NWIN * 64)) * DIM, lw, lb, g, af1);
    ln_tile(xin + (xbase + (size_t)(n0 + 2) * (NWIN * 64)) * DIM, lw, lb, g, af2);
    __syncthreads();    // W staged

    const f32x4 z = {0.f, 0.f, 0.f, 0.f};
    const float gs = 0.17677669529663687f;
    const int swz = (qc & 7) << 3;            // col&7 == qc&7 (ct*16 ≡ 0 mod 8)

#pragma unroll
    for (int ct = 0; ct < 8; ++ct) {
        const int col = ct * 16 + qc;
        short8 wf[4];
#pragma unroll
        for (int c = 0; c < 4; ++c)
            wf[c] = *(const short8*)&Wl[col * DIM + ((c * 32 + 8 * g) ^ swz)];

        f32x4 a0 = z, a1 = z, a2 = z;
        if (mode == 2) {
            // unswapped: D rows = tokens (4g+r), col = W-col qc -> [d][t] store
#pragma unroll
            for (int c = 0; c < 4; ++c) {
                a0 = __builtin_amdgcn_mfma_f32_16x16x32_bf16(af0[c], wf[c], a0, 0, 0, 0);
                a1 = __builtin_amdgcn_mfma_f32_16x16x32_bf16(af1[c], wf[c], a1, 0, 0, 0);
                a2 = __builtin_amdgcn_mfma_f32_16x16x32_bf16(af2[c], wf[c], a2, 0, 0, 0);
            }
            const int head = ct >> 1;
            const int d = (ct & 1) * 16 + qc;
            const float bb = bias[col];
            const size_t rowb = ((size_t)(b * NHEADS + head) * NWIN + l) * DHEAD + d;
            unsigned short* dst = outp + rowb * NTOK + T0 + 4 * g;
            ushort4 o;
            o.x = f2bf(a0[0] + bb); o.y = f2bf(a0[1] + bb);
            o.z = f2bf(a0[2] + bb); o.w = f2bf(a0[3] + bb);
            *(ushort4*)&dst[(n0 + 0) * 64] = o;
            o.x = f2bf(a1[0] + bb); o.y = f2bf(a1[1] + bb);
            o.z = f2bf(a1[2] + bb); o.w = f2bf(a1[3] + bb);
            *(ushort4*)&dst[(n0 + 1) * 64] = o;
            o.x = f2bf(a2[0] + bb); o.y = f2bf(a2[1] + bb);
            o.z = f2bf(a2[2] + bb); o.w = f2bf(a2[3] + bb);
            *(ushort4*)&dst[(n0 + 2) * 64] = o;
        } else {
            // swapped: D^T -> lane holds token qc, cols ct*16+4g..+3 (contig)
#pragma unroll
            for (int c = 0; c < 4; ++c) {
                a0 = __builtin_amdgcn_mfma_f32_16x16x32_bf16(wf[c], af0[c], a0, 0, 0, 0);
                a1 = __builtin_amdgcn_mfma_f32_16x16x32_bf16(wf[c], af1[c], a1, 0, 0, 0);
                a2 = __builtin_amdgcn_mfma_f32_16x16x32_bf16(wf[c], af2[c], a2, 0, 0, 0);
            }
            const int head = ct >> 1;                 // 4g+3 < 16: no head cross
            const int d0 = (ct & 1) * 16 + 4 * g;
            const float hs = (mode == 0) ? (gs * gate[head]) : 1.0f;
            const float4 b4 = *(const float4*)&bias[ct * 16 + 4 * g];
            const float bx = b4.x * hs, by = b4.y * hs, bz = b4.z * hs, bw = b4.w * hs;
            const size_t hb = (size_t)(b * NHEADS + head) * NWIN + l;
            unsigned short* dst = outp + (hb * NTOK + T0 + qc) * DHEAD + d0;
            ushort4 o;
            o.x = f2bf(a0[0] + bx); o.y = f2bf(a0[1] + by);
            o.z = f2bf(a0[2] + bz); o.w = f2bf(a0[3] + bw);
            *(ushort4*)&dst[(size_t)(n0 + 0) * 64 * DHEAD] = o;
            o.x = f2bf(a1[0] + bx); o.y = f2bf(a1[1] + by);
            o.z = f2bf(a1[2] + bz); o.w = f2bf(a1[3] + bw);
            *(ushort4*)&dst[(size_t)(n0 + 1) * 64 * DHEAD] = o;
            o.x = f2bf(a2[0] + bx); o.y = f2bf(a2[1] + by);
            o.z = f2bf(a2[2] + bz); o.w = f2bf(a2[3] + bw);
            *(ushort4*)&dst[(size_t)(n0 + 2) * 64 * DHEAD] = o;
        }
    }
}

// ---------------------------------------------------------------------------
// MFMA flash attention v3: one block per (b,h,window,q-half), 4 waves x 3
// q-tiles. Grid 1024 (4 blocks/CU). Per kc: K/V frags loaded once, 3
// independent S->exp->pack->write chains then 3 read->PV chains. No barriers.
// ---------------------------------------------------------------------------
__global__ __launch_bounds__(256) void attn_kernel(
    const unsigned short* __restrict__ qh, const unsigned short* __restrict__ kh,
    const unsigned short* __restrict__ vt, unsigned short* __restrict__ aout)
{
    __shared__ unsigned short P[4][3][16][40];   // 15 KB

    const int tid  = threadIdx.x;
    const int w    = tid >> 6;
    const int lane = tid & 63;
    const int g    = lane >> 4;
    const int qc   = lane & 15;

    const int idx = blockIdx.x;                  // b*512 + h*128 + l*2 + half
    const int b = idx >> 9, h = (idx >> 7) & 3, l = (idx >> 1) & 63, half = idx & 1;
    const size_t base = (size_t)((b * NHEADS + h) * NWIN + l) * (NTOK * DHEAD);
    const unsigned short* Qp = qh + base;
    const unsigned short* Kp = kh + base;
    const unsigned short* Vp = vt + base;        // [32][384]

    short8 qf[3];
#pragma unroll
    for (int j = 0; j < 3; ++j)
        qf[j] = *(const short8*)(Qp + (size_t)(((half * 4 + w) * 3 + j) * 16 + qc) * DHEAD + 8 * g);

    f32x4 o0[3], o1[3];
    float psum[3];
    const f32x4 z = {0.f, 0.f, 0.f, 0.f};
#pragma unroll
    for (int j = 0; j < 3; ++j) { o0[j] = z; o1[j] = z; psum[j] = 0.f; }

    for (int kc = 0; kc < 12; ++kc) {
        const int k0 = kc * 32;
        const short8 ka0 = *(const short8*)(Kp + (size_t)(k0 + qc) * DHEAD + 8 * g);
        const short8 ka1 = *(const short8*)(Kp + (size_t)(k0 + 16 + qc) * DHEAD + 8 * g);
        const short8 vb0 = *(const short8*)(Vp + (size_t)qc * NTOK + k0 + 8 * g);
        const short8 vb1 = *(const short8*)(Vp + (size_t)(16 + qc) * NTOK + k0 + 8 * g);

#pragma unroll
        for (int j = 0; j < 3; ++j) {
            f32x4 s0 = __builtin_amdgcn_mfma_f32_16x16x32_bf16(ka0, qf[j], z, 0, 0, 0);
            f32x4 s1 = __builtin_amdgcn_mfma_f32_16x16x32_bf16(ka1, qf[j], z, 0, 0, 0);
            const float e0 = __expf(s0[0]), e1 = __expf(s0[1]), e2 = __expf(s0[2]), e3 = __expf(s0[3]);
            const float e4 = __expf(s1[0]), e5 = __expf(s1[1]), e6 = __expf(s1[2]), e7 = __expf(s1[3]);
            psum[j] += ((e0 + e1) + (e2 + e3)) + ((e4 + e5) + (e6 + e7));
            ushort4 pw0, pw1;
            pw0.x = f2bf(e0); pw0.y = f2bf(e1); pw0.z = f2bf(e2); pw0.w = f2bf(e3);
            pw1.x = f2bf(e4); pw1.y = f2bf(e5); pw1.z = f2bf(e6); pw1.w = f2bf(e7);
            *(ushort4*)&P[w][j][qc][4 * g]      = pw0;
            *(ushort4*)&P[w][j][qc][16 + 4 * g] = pw1;
        }
#pragma unroll
        for (int j = 0; j < 3; ++j) {
            const short8 pa = *(const short8*)&P[w][j][qc][8 * g];
            o0[j] = __builtin_amdgcn_mfma_f32_16x16x32_bf16(pa, vb0, o0[j], 0, 0, 0);
            o1[j] = __builtin_amdgcn_mfma_f32_16x16x32_bf16(pa, vb1, o1[j], 0, 0, 0);
        }
    }

#pragma unroll
    for (int j = 0; j < 3; ++j) {
        float ps = psum[j];
        ps += __shfl_xor(ps, 16);
        ps += __shfl_xor(ps, 32);
        const float inv = 1.0f / ps;
        const int q0 = ((half * 4 + w) * 3 + j) * 16;
        const size_t ob = ((size_t)(b * NWIN + l) * NTOK + q0) * (NHEADS * DHEAD) + h * DHEAD + qc;
#pragma unroll
        for (int r = 0; r < 4; ++r) {
            const float iv = __shfl(inv, 4 * g + r);
            aout[ob + (size_t)(4 * g + r) * (NHEADS * DHEAD)]      = f2bf(o0[j][r] * iv);
            aout[ob + (size_t)(4 * g + r) * (NHEADS * DHEAD) + 16] = f2bf(o1[j][r] * iv);
        }
    }
}

// ---------------------------------------------------------------------------
// Output projection: mean over n commutes with (@ wp + bp). One block per
// (b, window, col-half) -> 256 blocks. a is bf16.
// ---------------------------------------------------------------------------
__global__ __launch_bounds__(256) void outproj_kernel(
    const unsigned short* __restrict__ a, const float* __restrict__ wp,
    const float* __restrict__ bp, const float* __restrict__ skip,
    float* __restrict__ outp)
{
    __shared__ float at[DIM * 68];       // abar transposed [dim][w], 34 KB
    __shared__ float wl[DIM * 64];       // [k][64 cols] 32 KB

    const int tid = threadIdx.x;
    const int bid = blockIdx.x;
    const int b = bid >> 7, l = (bid >> 1) & 63, cg = bid & 1;
    const int c0 = cg * 64;

#pragma unroll
    for (int rep = 0; rep < 8; ++rep) {
        const int idx = rep * 256 + tid;
        const int row = idx >> 4, cc4 = idx & 15;
        *(float4*)&wl[row * 64 + cc4 * 4] = *(const float4*)&wp[row * 128 + c0 + cc4 * 4];
    }

    const size_t abase = (size_t)(b * NWIN + l) * NTOK * DIM;
#pragma unroll
    for (int r = 0; r < 32; ++r) {
        const int f = tid + 256 * r;     // f = w*128 + d
        const int w_ = f >> 7, d = f & 127;
        float s = 0.f;
#pragma unroll
        for (int n = 0; n < NA; ++n)
            s += bf2f(a[abase + (size_t)(n * 64 + w_) * DIM + d]);
        at[d * 68 + w_] = s * (1.0f / 6.0f);
    }
    __syncthreads();

    const int cx = tid & 15, ty = tid >> 4;   // 4 cols x 4 tokens per thread
    float acc[4][4];
#pragma unroll
    for (int i = 0; i < 4; ++i)
#pragma unroll
        for (int j = 0; j < 4; ++j) acc[i][j] = 0.f;

#pragma unroll 4
    for (int i = 0; i < DIM; ++i) {
        const float4 wa = *(const float4*)&wl[i * 64 + 4 * cx];
        const float4 aa = *(const float4*)&at[i * 68 + 4 * ty];
        acc[0][0] += aa.x * wa.x; acc[0][1] += aa.x * wa.y; acc[0][2] += aa.x * wa.z; acc[0][3] += aa.x * wa.w;
        acc[1][0] += aa.y * wa.x; acc[1][1] += aa.y * wa.y; acc[1][2] += aa.y * wa.z; acc[1][3] += aa.y * wa.w;
        acc[2][0] += aa.z * wa.x; acc[2][1] += aa.z * wa.y; acc[2][2] += aa.z * wa.z; acc[2][3] += aa.z * wa.w;
        acc[3][0] += aa.w * wa.x; acc[3][1] += aa.w * wa.y; acc[3][2] += aa.w * wa.z; acc[3][3] += aa.w * wa.w;
    }

    const float4 bb = *(const float4*)&bp[c0 + 4 * cx];
#pragma unroll
    for (int u = 0; u < 4; ++u) {
        const int w_ = 4 * ty + u;
        const size_t oidx = ((size_t)(b * NWIN + l) * 64 + w_) * DIM + c0 + 4 * cx;
        const float4 sk = *(const float4*)&skip[oidx];
        float4 o;
        o.x = acc[u][0] + bb.x + sk.x;
        o.y = acc[u][1] + bb.y + sk.y;
        o.z = acc[u][2] + bb.z + sk.z;
        o.w = acc[u][3] + bb.w + sk.w;
        *(float4*)&outp[oidx] = o;
    }
}

extern "C" void kernel_launch(void* const* d_in, const int* in_sizes, int n_in,
                              void* d_out, int out_size, void* d_ws, size_t ws_size,
                              hipStream_t stream) {
    const float* q      = (const float*)d_in[0];
    const float* k      = (const float*)d_in[1];
    const float* v      = (const float*)d_in[2];
    const float* skip   = (const float*)d_in[3];
    const float* gate   = (const float*)d_in[4];
    const float* ln_q_w = (const float*)d_in[5];
    const float* ln_q_b = (const float*)d_in[6];
    const float* ln_k_w = (const float*)d_in[7];
    const float* ln_k_b = (const float*)d_in[8];
    const float* ln_v_w = (const float*)d_in[9];
    const float* ln_v_b = (const float*)d_in[10];
    const float* wq     = (const float*)d_in[11];
    const float* bq     = (const float*)d_in[12];
    const float* wk     = (const float*)d_in[13];
    const float* bk     = (const float*)d_in[14];
    const float* wv     = (const float*)d_in[15];
    const float* bv     = (const float*)d_in[16];
    const float* wp     = (const float*)d_in[17];
    const float* bp     = (const float*)d_in[18];
    float* outp = (float*)d_out;

    const size_t per = (size_t)NB * NHEADS * NWIN * NTOK * DHEAD;  // 6,291,456
    unsigned short* qh = (unsigned short*)d_ws;
    unsigned short* kh = qh + per;
    unsigned short* vh = kh + per;
    unsigned short* wt = vh + per;                 // 3*16384 bf16
    unsigned short* a  = wt + 3 * 16384;           // [b][l][t][128] bf16

    wconv_kernel<<<192, 256, 0, stream>>>(wq, wk, wv, gate, wt);
    proj_kernel<<<768, 256, 0, stream>>>(
        q, k, v, ln_q_w, ln_q_b, ln_k_w, ln_k_b, ln_v_w, ln_v_b,
        bq, bk, bv, gate, wt, qh, kh, vh);
    attn_kernel<<<NB * NHEADS * NWIN * 2, 256, 0, stream>>>(qh, kh, vh, a);
    outproj_kernel<<<NB * NWIN * 2, 256, 0, stream>>>(a, wp, bp, skip, outp);
}